// Round 1
// 827.153 us; speedup vs baseline: 1.0796x; 1.0796x over previous
//
#include <hip/hip_runtime.h>
#include <hip/hip_bf16.h>

using bf16 = __hip_bfloat16;
using short8 = __attribute__((ext_vector_type(8))) short;   // 8 bf16 (4 VGPRs)
using floatx4 = __attribute__((ext_vector_type(4))) float;  // 4 fp32 acc

#define NSEG 4
#define HID 768
#define INDIM 1536
#define NQKV 2304
#define NHEADS 8
#define HD 96

// fp32 -> bf16 bits, round-to-nearest-even
__device__ inline unsigned short f2b(float v) {
  union { float f; unsigned u; } c; c.f = v;
  unsigned r = c.u + 0x7FFF + ((c.u >> 16) & 1);
  return (unsigned short)(r >> 16);
}

// async global->LDS, 16B per lane. LDS dest must be wave-uniform base;
// each lane lands at base + lane*16. Global src is per-lane.
__device__ inline void gload16(const void* g, void* l) {
  __builtin_amdgcn_global_load_lds(
      (const __attribute__((address_space(1))) unsigned int*)g,
      (__attribute__((address_space(3))) unsigned int*)l, 16, 0, 0);
}

// ---------------------------------------------------------------------------
// Tiled transpose + fp32->bf16: src K x C fp32 row-major, dst C x K bf16.
// ---------------------------------------------------------------------------
__global__ __launch_bounds__(256) void transpose_w(
    const float* __restrict__ src, bf16* __restrict__ dst, int K, int C) {
  __shared__ unsigned short tile[32][33];
  const int c0 = blockIdx.x * 32, k0 = blockIdx.y * 32;
  const int tx = threadIdx.x, ty = threadIdx.y;  // 32 x 8
#pragma unroll
  for (int i = 0; i < 4; ++i)
    tile[ty + 8 * i][tx] = f2b(src[(size_t)(k0 + ty + 8 * i) * C + c0 + tx]);
  __syncthreads();
  unsigned short* d = (unsigned short*)dst;
#pragma unroll
  for (int i = 0; i < 4; ++i)
    d[(size_t)(c0 + ty + 8 * i) * K + k0 + tx] = tile[tx][ty + 8 * i];
}

// ---------------------------------------------------------------------------
// One-time fp32 -> bf16 cast of x (same memory order). Memory-bound.
// ---------------------------------------------------------------------------
__global__ __launch_bounds__(256) void convert_x(
    const float* __restrict__ x, bf16* __restrict__ xb) {
  const size_t i = ((size_t)blockIdx.x * 256 + threadIdx.x) * 8;
  float4 a = *(const float4*)(x + i);
  float4 b = *(const float4*)(x + i + 4);
  union { uint4 u; unsigned short s[8]; } r;
  r.s[0] = f2b(a.x); r.s[1] = f2b(a.y); r.s[2] = f2b(a.z); r.s[3] = f2b(a.w);
  r.s[4] = f2b(b.x); r.s[5] = f2b(b.y); r.s[6] = f2b(b.z); r.s[7] = f2b(b.w);
  *(uint4*)(xb + i) = r.u;
}

// ---------------------------------------------------------------------------
// GEMM1: QKV[m][c] = sum_e A[m][e] * Wqkv[e][c];  m = r*4+n, e = p*64+d.
// A gathered from bf16 xb (B,T,H,W,D) via per-lane global_load_lds src.
// wT = Wqkv^T [2304][1536] bf16. 128x128 tile, BK=32, 4 waves, m97 structure.
// ---------------------------------------------------------------------------
__global__ __launch_bounds__(256, 2) void gemm_qkv(
    const bf16* __restrict__ xb, const bf16* __restrict__ wT,
    bf16* __restrict__ qkv) {
  __shared__ __align__(16) short As[128 * 32];  // linear [128][32], 8 KB
  __shared__ __align__(16) short Bs[128 * 32];
  const int tid = threadIdx.x;
  const int n0 = blockIdx.x * 128;
  const int m0 = blockIdx.y * 128;
  const int lane = tid & 63, wave = tid >> 6;
  const int wm = (wave >> 1) * 64, wn = (wave & 1) * 64;
  const int l15 = lane & 15, quad = lane >> 4;
  // staging geometry: wave w covers rows [w*16, w*16+16) of each 64-row half;
  // lane l -> row w*16 + l/4, col (l&3)*8 (bf16). dest byte = base + lane*16.
  const int srow = wave * 16 + (lane >> 2);
  const int sch = (lane & 3) * 8;
  floatx4 acc[4][4] = {};

  // A-gather decomposition for both 64-row halves (k-independent part)
  const int mA0 = m0 + srow, mA1 = m0 + 64 + srow;
  const int rA0 = mA0 >> 2, nA0 = mA0 & 3;
  const int rA1 = mA1 >> 2, nA1 = mA1 & 3;
  const size_t baseA0 =
      ((size_t)((rA0 >> 10) * 96 + nA0 * 24) * 1024 + (rA0 & 1023)) * 64;
  const size_t baseA1 =
      ((size_t)((rA1 >> 10) * 96 + nA1 * 24) * 1024 + (rA1 & 1023)) * 64;
  const bf16* bB0 = wT + (size_t)(n0 + srow) * INDIM + sch;
  const bf16* bB1 = wT + (size_t)(n0 + 64 + srow) * INDIM + sch;

  short* asb0 = &As[wave * 512];         // wave-uniform LDS bases
  short* asb1 = &As[2048 + wave * 512];
  short* bsb0 = &Bs[wave * 512];
  short* bsb1 = &Bs[2048 + wave * 512];

  for (int kt = 0; kt < 48; ++kt) {
    const int k0 = kt * 32;
    const int p = kt >> 1;                     // e = p*64 + d
    const int dlo = (kt & 1) * 32 + sch;       // d within the 64-block
    __syncthreads();
    gload16(xb + baseA0 + (size_t)p * 65536 + dlo, asb0);
    gload16(xb + baseA1 + (size_t)p * 65536 + dlo, asb1);
    gload16(bB0 + k0, bsb0);
    gload16(bB1 + k0, bsb1);
    __syncthreads();  // drains vmcnt -> staging complete
    short8 af[4], bg[4];
#pragma unroll
    for (int t = 0; t < 4; ++t) {
      af[t] = *(const short8*)&As[(wm + t * 16 + l15) * 32 + quad * 8];
      bg[t] = *(const short8*)&Bs[(wn + t * 16 + l15) * 32 + quad * 8];
    }
#pragma unroll
    for (int ti = 0; ti < 4; ++ti)
#pragma unroll
      for (int tj = 0; tj < 4; ++tj)
        acc[ti][tj] = __builtin_amdgcn_mfma_f32_16x16x32_bf16(
            af[ti], bg[tj], acc[ti][tj], 0, 0, 0);
  }
  // epilogue: C/D layout col=lane&15, row=quad*4+reg
#pragma unroll
  for (int ti = 0; ti < 4; ++ti)
#pragma unroll
    for (int tj = 0; tj < 4; ++tj)
#pragma unroll
      for (int reg = 0; reg < 4; ++reg) {
        const int row = m0 + wm + ti * 16 + quad * 4 + reg;
        const int col = n0 + wn + tj * 16 + l15;
        qkv[(size_t)row * NQKV + col] = __float2bfloat16(acc[ti][tj][reg]);
      }
}

// ---------------------------------------------------------------------------
// Attention per row r: RoPE(q,k), per-head 4x4 softmax, O = attn @ v (bf16).
// ---------------------------------------------------------------------------
__global__ __launch_bounds__(256) void attn_kernel(
    const bf16* __restrict__ qkv, const float* __restrict__ fcos,
    const float* __restrict__ fsin, bf16* __restrict__ obuf) {
  constexpr int SF_LD = 2312;  // pad 2304->2312 (bank offset 8 per row)
  __shared__ float sf[NSEG][SF_LD];  // [n][0:768)=q [768:1536)=k [1536:2304)=v
  __shared__ float ssc[NHEADS][NSEG][NSEG];
  __shared__ float sat[NHEADS][NSEG][NSEG];
  const int r = blockIdx.x;
  const int tid = threadIdx.x;
  const bf16* base = qkv + (size_t)r * NSEG * NQKV;

  for (int cid = tid; cid < (NSEG * NQKV) / 8; cid += 256) {
    const int n = cid / (NQKV / 8);
    const int c = (cid % (NQKV / 8)) * 8;
    uint4 u = *(const uint4*)(base + (size_t)n * NQKV + c);
    const bf16* h = reinterpret_cast<const bf16*>(&u);
#pragma unroll
    for (int j = 0; j < 8; ++j) sf[n][c + j] = __bfloat162float(h[j]);
  }
  __syncthreads();

  // RoPE on q and k
  for (int idx = tid; idx < NSEG * (HID / 2); idx += 256) {
    const int n = idx / (HID / 2), j = idx % (HID / 2);
    const float c = fcos[n * (HID / 2) + j];
    const float s = fsin[n * (HID / 2) + j];
    float q0 = sf[n][2 * j], q1 = sf[n][2 * j + 1];
    sf[n][2 * j] = q0 * c - q1 * s;
    sf[n][2 * j + 1] = q0 * s + q1 * c;
    float k0 = sf[n][HID + 2 * j], k1 = sf[n][HID + 2 * j + 1];
    sf[n][HID + 2 * j] = k0 * c - k1 * s;
    sf[n][HID + 2 * j + 1] = k0 * s + k1 * c;
  }
  __syncthreads();

  // scores: 8 heads x 4 x 4 dots of length 96
  if (tid < 128) {
    const int h = tid >> 4, n = (tid >> 2) & 3, m = tid & 3;
    const float* qp = &sf[n][h * HD];
    const float* kp = &sf[m][HID + h * HD];
    float s = 0.f;
#pragma unroll 8
    for (int i = 0; i < HD; ++i) s += qp[i] * kp[i];
    ssc[h][n][m] = s * 0.10206207261596575f;  // 1/sqrt(96)
  }
  __syncthreads();

  if (tid < 32) {
    const int h = tid >> 2, n = tid & 3;
    float mx = ssc[h][n][0];
#pragma unroll
    for (int m = 1; m < 4; ++m) mx = fmaxf(mx, ssc[h][n][m]);
    float e[4], sum = 0.f;
#pragma unroll
    for (int m = 0; m < 4; ++m) { e[m] = __expf(ssc[h][n][m] - mx); sum += e[m]; }
    const float inv = 1.f / sum;
#pragma unroll
    for (int m = 0; m < 4; ++m) sat[h][n][m] = e[m] * inv;
  }
  __syncthreads();

  for (int idx = tid; idx < NSEG * HID; idx += 256) {
    const int n = idx / HID, c = idx % HID, h = c / HD;
    float s = 0.f;
#pragma unroll
    for (int m = 0; m < 4; ++m) s += sat[h][n][m] * sf[m][2 * HID + c];
    obuf[((size_t)r * NSEG + n) * HID + c] = __float2bfloat16(s);
  }
}

// ---------------------------------------------------------------------------
// GEMM2: out = O @ Wo + bo, fused scatter into (B,T,H,W,D) fp32 output.
//   A = obuf [32768][768] bf16, wT = Wo^T [1536][768] bf16, bo fp32.
//   Same m97 global_load_lds structure.
// ---------------------------------------------------------------------------
__global__ __launch_bounds__(256, 2) void gemm_out(
    const bf16* __restrict__ A, const bf16* __restrict__ wT,
    const float* __restrict__ bo, float* __restrict__ out) {
  __shared__ __align__(16) short As[128 * 32];
  __shared__ __align__(16) short Bs[128 * 32];
  const int tid = threadIdx.x;
  const int n0 = blockIdx.x * 128;
  const int m0 = blockIdx.y * 128;
  const int lane = tid & 63, wave = tid >> 6;
  const int wm = (wave >> 1) * 64, wn = (wave & 1) * 64;
  const int l15 = lane & 15, quad = lane >> 4;
  const int srow = wave * 16 + (lane >> 2);
  const int sch = (lane & 3) * 8;
  floatx4 acc[4][4] = {};

  const bf16* aB0 = A + (size_t)(m0 + srow) * HID + sch;
  const bf16* aB1 = A + (size_t)(m0 + 64 + srow) * HID + sch;
  const bf16* bB0 = wT + (size_t)(n0 + srow) * HID + sch;
  const bf16* bB1 = wT + (size_t)(n0 + 64 + srow) * HID + sch;

  short* asb0 = &As[wave * 512];
  short* asb1 = &As[2048 + wave * 512];
  short* bsb0 = &Bs[wave * 512];
  short* bsb1 = &Bs[2048 + wave * 512];

  for (int kt = 0; kt < 24; ++kt) {
    const int k0 = kt * 32;
    __syncthreads();
    gload16(aB0 + k0, asb0);
    gload16(aB1 + k0, asb1);
    gload16(bB0 + k0, bsb0);
    gload16(bB1 + k0, bsb1);
    __syncthreads();
    short8 af[4], bg[4];
#pragma unroll
    for (int t = 0; t < 4; ++t) {
      af[t] = *(const short8*)&As[(wm + t * 16 + l15) * 32 + quad * 8];
      bg[t] = *(const short8*)&Bs[(wn + t * 16 + l15) * 32 + quad * 8];
    }
#pragma unroll
    for (int ti = 0; ti < 4; ++ti)
#pragma unroll
      for (int tj = 0; tj < 4; ++tj)
        acc[ti][tj] = __builtin_amdgcn_mfma_f32_16x16x32_bf16(
            af[ti], bg[tj], acc[ti][tj], 0, 0, 0);
  }
  // epilogue: bias + scatter to (B,T,H,W,D) fp32: t = n*24+p
#pragma unroll
  for (int ti = 0; ti < 4; ++ti)
#pragma unroll
    for (int tj = 0; tj < 4; ++tj)
#pragma unroll
      for (int reg = 0; reg < 4; ++reg) {
        const int row = m0 + wm + ti * 16 + quad * 4 + reg;
        const int col = n0 + wn + tj * 16 + l15;
        const float v = acc[ti][tj][reg] + bo[col];
        const int r = row >> 2, n = row & 3;
        const int b = r >> 10, hw = r & 1023;
        const int p = col >> 6, d = col & 63;
        const size_t dst =
            ((size_t)((b * 96 + n * 24 + p) * 1024 + hw)) * 64 + d;
        out[dst] = v;
      }
}

// ---------------------------------------------------------------------------
extern "C" void kernel_launch(void* const* d_in, const int* in_sizes, int n_in,
                              void* d_out, int out_size, void* d_ws,
                              size_t ws_size, hipStream_t stream) {
  const float* x = (const float*)d_in[0];     // (8,96,32,32,64) fp32
  const float* fcos = (const float*)d_in[1];  // (4,384) fp32
  const float* fsin = (const float*)d_in[2];  // (4,384) fp32
  const float* Wq = (const float*)d_in[3];    // (1536,768) fp32
  const float* Wk = (const float*)d_in[4];
  const float* Wv = (const float*)d_in[5];
  const float* Wo = (const float*)d_in[6];    // (768,1536) fp32
  const float* bo = (const float*)d_in[7];    // (1536,) fp32
  float* out = (float*)d_out;                 // (8,96,32,32,64) fp32

  char* ws = (char*)d_ws;
  bf16* wqkvT = (bf16*)ws;                        // 2304*1536*2 = 7,077,888 B
  bf16* woT = (bf16*)(ws + 7077888);              // 1536*768*2  = 2,359,296 B
  bf16* qkv = (bf16*)(ws + 9437184);              // 32768*2304*2 = 150,994,944 B
  bf16* obuf = (bf16*)(ws + 160432128);           // 32768*768*2  = 50,331,648 B
  // xb (bf16 cast of x, 100,663,296 B) lives in d_out scratch: its lifetime
  // ends before gemm_out, which overwrites every element of d_out.
  bf16* xb = (bf16*)d_out;

  dim3 tb(32, 8);
  transpose_w<<<dim3(24, 48), tb, 0, stream>>>(Wq, wqkvT, INDIM, HID);
  transpose_w<<<dim3(24, 48), tb, 0, stream>>>(Wk, wqkvT + (size_t)HID * INDIM, INDIM, HID);
  transpose_w<<<dim3(24, 48), tb, 0, stream>>>(Wv, wqkvT + (size_t)2 * HID * INDIM, INDIM, HID);
  transpose_w<<<dim3(48, 24), tb, 0, stream>>>(Wo, woT, HID, INDIM);

  convert_x<<<24576, 256, 0, stream>>>(x, xb);
  gemm_qkv<<<dim3(18, 256), 256, 0, stream>>>(xb, wqkvT, qkv);
  attn_kernel<<<8192, 256, 0, stream>>>(qkv, fcos, fsin, obuf);
  gemm_out<<<dim3(12, 256), 256, 0, stream>>>(obuf, woT, bo, out);
}

// Round 2
// 706.535 us; speedup vs baseline: 1.2639x; 1.1707x over previous
//
#include <hip/hip_runtime.h>
#include <hip/hip_bf16.h>

using bf16 = __hip_bfloat16;
using short8 = __attribute__((ext_vector_type(8))) short;   // 8 bf16 (4 VGPRs)
using floatx4 = __attribute__((ext_vector_type(4))) float;  // 4 fp32 acc

#define NSEG 4
#define HID 768
#define INDIM 1536
#define NQKV 2304
#define NHEADS 8
#define HD 96

// fp32 -> bf16 bits, round-to-nearest-even
__device__ inline unsigned short f2b(float v) {
  union { float f; unsigned u; } c; c.f = v;
  unsigned r = c.u + 0x7FFF + ((c.u >> 16) & 1);
  return (unsigned short)(r >> 16);
}

// async global->LDS, 16B per lane: dest = wave-uniform base + lane*16.
__device__ inline void gload16(const void* g, void* l) {
  __builtin_amdgcn_global_load_lds(
      (const __attribute__((address_space(1))) unsigned int*)g,
      (__attribute__((address_space(3))) unsigned int*)l, 16, 0, 0);
}

#define MEMFENCE asm volatile("" ::: "memory")
#define BARRIER do { MEMFENCE; __builtin_amdgcn_s_barrier(); MEMFENCE; } while (0)

// ---------------------------------------------------------------------------
// 8-phase 256x256 GEMM phase body (shared by both GEMMs).
// Expects in scope: lds, lA, lB, acc[8][4], bfr[4][2].
// LDS layout per parity: A at par*65536, B at 32768+par*65536; within a tile:
// [kh][row][32 bf16] (64B rows), st_16x32 swizzle: colbyte ^= 32 when row&8.
// ---------------------------------------------------------------------------
#define PHASE(par, q, LOADB, STAGES, VMW) do {                                 \
    short8 a00 = *(const short8*)(lA + (par)*65536 + (q)*2048);                \
    short8 a01 = *(const short8*)(lA + (par)*65536 + (q)*2048 + 16384);        \
    short8 a10 = *(const short8*)(lA + (par)*65536 + (q)*2048 + 1024);         \
    short8 a11 = *(const short8*)(lA + (par)*65536 + (q)*2048 + 1024 + 16384); \
    if (LOADB) {                                                               \
      _Pragma("unroll")                                                        \
      for (int fn = 0; fn < 4; ++fn) {                                         \
        bfr[fn][0] = *(const short8*)(lB + (par)*65536 + fn*1024);             \
        bfr[fn][1] = *(const short8*)(lB + (par)*65536 + fn*1024 + 16384);     \
      }                                                                        \
    }                                                                          \
    STAGES;                                                                    \
    BARRIER;                                                                   \
    __builtin_amdgcn_s_setprio(1);                                             \
    _Pragma("unroll")                                                          \
    for (int fn = 0; fn < 4; ++fn) {                                           \
      acc[2*(q)][fn]   = __builtin_amdgcn_mfma_f32_16x16x32_bf16(              \
          a00, bfr[fn][0], acc[2*(q)][fn], 0, 0, 0);                           \
      acc[2*(q)][fn]   = __builtin_amdgcn_mfma_f32_16x16x32_bf16(              \
          a01, bfr[fn][1], acc[2*(q)][fn], 0, 0, 0);                           \
      acc[2*(q)+1][fn] = __builtin_amdgcn_mfma_f32_16x16x32_bf16(              \
          a10, bfr[fn][0], acc[2*(q)+1][fn], 0, 0, 0);                         \
      acc[2*(q)+1][fn] = __builtin_amdgcn_mfma_f32_16x16x32_bf16(              \
          a11, bfr[fn][1], acc[2*(q)+1][fn], 0, 0, 0);                         \
    }                                                                          \
    __builtin_amdgcn_s_setprio(0);                                             \
    VMW;                                                                       \
    BARRIER;                                                                   \
  } while (0)

#define VM4 do { asm volatile("s_waitcnt vmcnt(4)" ::: "memory"); } while (0)
#define VM0 do { asm volatile("s_waitcnt vmcnt(0)" ::: "memory"); } while (0)

// ---------------------------------------------------------------------------
// Tiled transpose + fp32->bf16: src K x C fp32 row-major, dst C x K bf16.
// ---------------------------------------------------------------------------
__global__ __launch_bounds__(256) void transpose_w(
    const float* __restrict__ src, bf16* __restrict__ dst, int K, int C) {
  __shared__ unsigned short tile[32][33];
  const int c0 = blockIdx.x * 32, k0 = blockIdx.y * 32;
  const int tx = threadIdx.x, ty = threadIdx.y;  // 32 x 8
#pragma unroll
  for (int i = 0; i < 4; ++i)
    tile[ty + 8 * i][tx] = f2b(src[(size_t)(k0 + ty + 8 * i) * C + c0 + tx]);
  __syncthreads();
  unsigned short* d = (unsigned short*)dst;
#pragma unroll
  for (int i = 0; i < 4; ++i)
    d[(size_t)(c0 + ty + 8 * i) * K + k0 + tx] = tile[tx][ty + 8 * i];
}

// ---------------------------------------------------------------------------
// One-time fp32 -> bf16 cast of x (same memory order). Memory-bound.
// ---------------------------------------------------------------------------
__global__ __launch_bounds__(256) void convert_x(
    const float* __restrict__ x, bf16* __restrict__ xb) {
  const size_t i = ((size_t)blockIdx.x * 256 + threadIdx.x) * 8;
  float4 a = *(const float4*)(x + i);
  float4 b = *(const float4*)(x + i + 4);
  union { uint4 u; unsigned short s[8]; } r;
  r.s[0] = f2b(a.x); r.s[1] = f2b(a.y); r.s[2] = f2b(a.z); r.s[3] = f2b(a.w);
  r.s[4] = f2b(b.x); r.s[5] = f2b(b.y); r.s[6] = f2b(b.z); r.s[7] = f2b(b.w);
  *(uint4*)(xb + i) = r.u;
}

// ---------------------------------------------------------------------------
// GEMM1: QKV[m][c] = sum_e A[m][e] * Wqkv[e][c]; 256x256 tile, 8-phase.
// A gathered from bf16 xb (B,T,H,W,D); BK=64 aligns with D=64 (p = kt).
// wT = Wqkv^T [2304][1536] bf16.
// ---------------------------------------------------------------------------
__global__ __launch_bounds__(512, 2) void gemm_qkv(
    const bf16* __restrict__ xb, const bf16* __restrict__ wT,
    bf16* __restrict__ qkv) {
  __shared__ __align__(16) char lds[131072];  // A0|B0|A1|B1, 32KB each
  const int tid = threadIdx.x;
  const int lane = tid & 63, wave = tid >> 6;
  const int wr = wave >> 2, wc = wave & 3;
  const int l15 = lane & 15, quad = lane >> 4;

  // XCD-aware block swizzle: 1152 blocks = 8 XCDs x 144
  const int lt = (blockIdx.x & 7) * 144 + (blockIdx.x >> 3);
  const int n0 = (lt % 9) * 256;
  const int m0 = (lt / 9) * 256;

  // --- staging source precompute (per-lane, kt-invariant) ---
  const int srow = wave * 16 + (lane >> 2);                 // 0..127 in half
  const int dswz = ((lane & 3) * 8) ^ ((lane & 32) >> 1);   // swizzled col
  const bf16* asrc[2];
  const bf16* bsrc[2];
#pragma unroll
  for (int h = 0; h < 2; ++h) {
    const int m = m0 + h * 128 + srow;
    const int r = m >> 2, n = m & 3;
    const int b = r >> 10, hw = r & 1023;
    asrc[h] = xb + ((size_t)((b * 96 + n * 24) * 1024 + hw)) * 64 + dswz;
    bsrc[h] = wT + (size_t)(n0 + h * 128 + srow) * INDIM + dswz;
  }
  char* sdst = lds + wave * 1024;  // wave-uniform LDS stage base

#define STAGE_QA(kt, h) do {                                   \
    char* d_ = sdst + (((kt) & 1) * 65536) + (h) * 8192;       \
    const bf16* s_ = asrc[h] + (size_t)(kt) * 65536;           \
    gload16(s_, d_);                                           \
    gload16(s_ + 32, d_ + 16384);                              \
  } while (0)
#define STAGE_QB(kt, h) do {                                   \
    char* d_ = sdst + 32768 + (((kt) & 1) * 65536) + (h) * 8192; \
    const bf16* s_ = bsrc[h] + (size_t)(kt) * 64;              \
    gload16(s_, d_);                                           \
    gload16(s_ + 32, d_ + 16384);                              \
  } while (0)

  // --- ds_read bases (swizzle is lane-constant: row&8 == l15&8) ---
  const int lofs = l15 * 64 + ((quad * 16) ^ ((l15 & 8) << 2));
  const char* lA = lds + wr * 8192 + lofs;
  const char* lB = lds + 32768 + wc * 4096 + lofs;

  floatx4 acc[8][4] = {};
  short8 bfr[4][2];

  // prologue: K0 fully + K1.B; land K0, keep K1.B in flight
  STAGE_QB(0, 0); STAGE_QB(0, 1); STAGE_QA(0, 0); STAGE_QA(0, 1);
  STAGE_QB(1, 0); STAGE_QB(1, 1);
  VM4;
  BARRIER;

  const int NKT = 24;
  for (int i = 0; i < 12; ++i) {
    const int a = 2 * i;
    PHASE(0, 0, 1, { STAGE_QA(a + 1, 0); }, {});
    PHASE(0, 1, 0, { STAGE_QA(a + 1, 1); }, {});
    PHASE(0, 2, 0, { if (a + 2 < NKT) STAGE_QB(a + 2, 0); }, {});
    PHASE(0, 3, 0, { if (a + 2 < NKT) STAGE_QB(a + 2, 1); },
          { if (a + 2 < NKT) VM4; else VM0; });
    PHASE(1, 0, 1, { if (a + 2 < NKT) STAGE_QA(a + 2, 0); }, {});
    PHASE(1, 1, 0, { if (a + 2 < NKT) STAGE_QA(a + 2, 1); }, {});
    PHASE(1, 2, 0, { if (a + 3 < NKT) STAGE_QB(a + 3, 0); }, {});
    PHASE(1, 3, 0, { if (a + 3 < NKT) STAGE_QB(a + 3, 1); },
          { if (a + 3 < NKT) VM4; else VM0; });
  }
#undef STAGE_QA
#undef STAGE_QB

  // epilogue: C/D layout col=lane&15, row=quad*4+reg
#pragma unroll
  for (int fm = 0; fm < 8; ++fm)
#pragma unroll
    for (int fn = 0; fn < 4; ++fn)
#pragma unroll
      for (int reg = 0; reg < 4; ++reg) {
        const int row = m0 + wr * 128 + fm * 16 + quad * 4 + reg;
        const int col = n0 + wc * 64 + fn * 16 + l15;
        qkv[(size_t)row * NQKV + col] = __float2bfloat16(acc[fm][fn][reg]);
      }
}

// ---------------------------------------------------------------------------
// Attention per row r: RoPE(q,k), per-head 4x4 softmax, O = attn @ v (bf16).
// ---------------------------------------------------------------------------
__global__ __launch_bounds__(256) void attn_kernel(
    const bf16* __restrict__ qkv, const float* __restrict__ fcos,
    const float* __restrict__ fsin, bf16* __restrict__ obuf) {
  constexpr int SF_LD = 2312;  // pad 2304->2312 (bank offset 8 per row)
  __shared__ float sf[NSEG][SF_LD];  // [n][0:768)=q [768:1536)=k [1536:2304)=v
  __shared__ float ssc[NHEADS][NSEG][NSEG];
  __shared__ float sat[NHEADS][NSEG][NSEG];
  const int r = blockIdx.x;
  const int tid = threadIdx.x;
  const bf16* base = qkv + (size_t)r * NSEG * NQKV;

  for (int cid = tid; cid < (NSEG * NQKV) / 8; cid += 256) {
    const int n = cid / (NQKV / 8);
    const int c = (cid % (NQKV / 8)) * 8;
    uint4 u = *(const uint4*)(base + (size_t)n * NQKV + c);
    const bf16* h = reinterpret_cast<const bf16*>(&u);
#pragma unroll
    for (int j = 0; j < 8; ++j) sf[n][c + j] = __bfloat162float(h[j]);
  }
  __syncthreads();

  // RoPE on q and k
  for (int idx = tid; idx < NSEG * (HID / 2); idx += 256) {
    const int n = idx / (HID / 2), j = idx % (HID / 2);
    const float c = fcos[n * (HID / 2) + j];
    const float s = fsin[n * (HID / 2) + j];
    float q0 = sf[n][2 * j], q1 = sf[n][2 * j + 1];
    sf[n][2 * j] = q0 * c - q1 * s;
    sf[n][2 * j + 1] = q0 * s + q1 * c;
    float k0 = sf[n][HID + 2 * j], k1 = sf[n][HID + 2 * j + 1];
    sf[n][HID + 2 * j] = k0 * c - k1 * s;
    sf[n][HID + 2 * j + 1] = k0 * s + k1 * c;
  }
  __syncthreads();

  // scores: 8 heads x 4 x 4 dots of length 96
  if (tid < 128) {
    const int h = tid >> 4, n = (tid >> 2) & 3, m = tid & 3;
    const float* qp = &sf[n][h * HD];
    const float* kp = &sf[m][HID + h * HD];
    float s = 0.f;
#pragma unroll 8
    for (int i = 0; i < HD; ++i) s += qp[i] * kp[i];
    ssc[h][n][m] = s * 0.10206207261596575f;  // 1/sqrt(96)
  }
  __syncthreads();

  if (tid < 32) {
    const int h = tid >> 2, n = tid & 3;
    float mx = ssc[h][n][0];
#pragma unroll
    for (int m = 1; m < 4; ++m) mx = fmaxf(mx, ssc[h][n][m]);
    float e[4], sum = 0.f;
#pragma unroll
    for (int m = 0; m < 4; ++m) { e[m] = __expf(ssc[h][n][m] - mx); sum += e[m]; }
    const float inv = 1.f / sum;
#pragma unroll
    for (int m = 0; m < 4; ++m) sat[h][n][m] = e[m] * inv;
  }
  __syncthreads();

  for (int idx = tid; idx < NSEG * HID; idx += 256) {
    const int n = idx / HID, c = idx % HID, h = c / HD;
    float s = 0.f;
#pragma unroll
    for (int m = 0; m < 4; ++m) s += sat[h][n][m] * sf[m][2 * HID + c];
    obuf[((size_t)r * NSEG + n) * HID + c] = __float2bfloat16(s);
  }
}

// ---------------------------------------------------------------------------
// GEMM2: out = O @ Wo + bo, fused scatter into (B,T,H,W,D) fp32 output.
//   A = obuf [32768][768] bf16, wT = Wo^T [1536][768] bf16. 8-phase 256x256.
// ---------------------------------------------------------------------------
__global__ __launch_bounds__(512, 2) void gemm_out(
    const bf16* __restrict__ Ao, const bf16* __restrict__ wT,
    const float* __restrict__ bo, float* __restrict__ out) {
  __shared__ __align__(16) char lds[131072];
  const int tid = threadIdx.x;
  const int lane = tid & 63, wave = tid >> 6;
  const int wr = wave >> 2, wc = wave & 3;
  const int l15 = lane & 15, quad = lane >> 4;

  // XCD-aware block swizzle: 768 blocks = 8 XCDs x 96
  const int lt = (blockIdx.x & 7) * 96 + (blockIdx.x >> 3);
  const int n0 = (lt % 6) * 256;
  const int m0 = (lt / 6) * 256;

  const int srow = wave * 16 + (lane >> 2);
  const int dswz = ((lane & 3) * 8) ^ ((lane & 32) >> 1);
  const bf16* asrc[2];
  const bf16* bsrc[2];
#pragma unroll
  for (int h = 0; h < 2; ++h) {
    asrc[h] = Ao + (size_t)(m0 + h * 128 + srow) * HID + dswz;
    bsrc[h] = wT + (size_t)(n0 + h * 128 + srow) * HID + dswz;
  }
  char* sdst = lds + wave * 1024;

#define STAGE_OA(kt, h) do {                                   \
    char* d_ = sdst + (((kt) & 1) * 65536) + (h) * 8192;       \
    const bf16* s_ = asrc[h] + (size_t)(kt) * 64;              \
    gload16(s_, d_);                                           \
    gload16(s_ + 32, d_ + 16384);                              \
  } while (0)
#define STAGE_OB(kt, h) do {                                   \
    char* d_ = sdst + 32768 + (((kt) & 1) * 65536) + (h) * 8192; \
    const bf16* s_ = bsrc[h] + (size_t)(kt) * 64;              \
    gload16(s_, d_);                                           \
    gload16(s_ + 32, d_ + 16384);                              \
  } while (0)

  const int lofs = l15 * 64 + ((quad * 16) ^ ((l15 & 8) << 2));
  const char* lA = lds + wr * 8192 + lofs;
  const char* lB = lds + 32768 + wc * 4096 + lofs;

  floatx4 acc[8][4] = {};
  short8 bfr[4][2];

  STAGE_OB(0, 0); STAGE_OB(0, 1); STAGE_OA(0, 0); STAGE_OA(0, 1);
  STAGE_OB(1, 0); STAGE_OB(1, 1);
  VM4;
  BARRIER;

  const int NKT = 12;
  for (int i = 0; i < 6; ++i) {
    const int a = 2 * i;
    PHASE(0, 0, 1, { STAGE_OA(a + 1, 0); }, {});
    PHASE(0, 1, 0, { STAGE_OA(a + 1, 1); }, {});
    PHASE(0, 2, 0, { if (a + 2 < NKT) STAGE_OB(a + 2, 0); }, {});
    PHASE(0, 3, 0, { if (a + 2 < NKT) STAGE_OB(a + 2, 1); },
          { if (a + 2 < NKT) VM4; else VM0; });
    PHASE(1, 0, 1, { if (a + 2 < NKT) STAGE_OA(a + 2, 0); }, {});
    PHASE(1, 1, 0, { if (a + 2 < NKT) STAGE_OA(a + 2, 1); }, {});
    PHASE(1, 2, 0, { if (a + 3 < NKT) STAGE_OB(a + 3, 0); }, {});
    PHASE(1, 3, 0, { if (a + 3 < NKT) STAGE_OB(a + 3, 1); },
          { if (a + 3 < NKT) VM4; else VM0; });
  }
#undef STAGE_OA
#undef STAGE_OB

  // epilogue: bias + scatter to (B,T,H,W,D) fp32: t = n*24+p
#pragma unroll
  for (int fm = 0; fm < 8; ++fm)
#pragma unroll
    for (int fn = 0; fn < 4; ++fn)
#pragma unroll
      for (int reg = 0; reg < 4; ++reg) {
        const int row = m0 + wr * 128 + fm * 16 + quad * 4 + reg;
        const int col = n0 + wc * 64 + fn * 16 + l15;
        const float v = acc[fm][fn][reg] + bo[col];
        const int r = row >> 2, n = row & 3;
        const int b = r >> 10, hw = r & 1023;
        const int p = col >> 6, d = col & 63;
        const size_t dst =
            ((size_t)((b * 96 + n * 24 + p) * 1024 + hw)) * 64 + d;
        out[dst] = v;
      }
}

// ---------------------------------------------------------------------------
extern "C" void kernel_launch(void* const* d_in, const int* in_sizes, int n_in,
                              void* d_out, int out_size, void* d_ws,
                              size_t ws_size, hipStream_t stream) {
  const float* x = (const float*)d_in[0];     // (8,96,32,32,64) fp32
  const float* fcos = (const float*)d_in[1];  // (4,384) fp32
  const float* fsin = (const float*)d_in[2];  // (4,384) fp32
  const float* Wq = (const float*)d_in[3];    // (1536,768) fp32
  const float* Wk = (const float*)d_in[4];
  const float* Wv = (const float*)d_in[5];
  const float* Wo = (const float*)d_in[6];    // (768,1536) fp32
  const float* bo = (const float*)d_in[7];    // (1536,) fp32
  float* out = (float*)d_out;                 // (8,96,32,32,64) fp32

  char* ws = (char*)d_ws;
  bf16* wqkvT = (bf16*)ws;                        // 2304*1536*2 = 7,077,888 B
  bf16* woT = (bf16*)(ws + 7077888);              // 1536*768*2  = 2,359,296 B
  bf16* qkv = (bf16*)(ws + 9437184);              // 32768*2304*2 = 150,994,944 B
  bf16* obuf = (bf16*)(ws + 160432128);           // 32768*768*2  = 50,331,648 B
  // xb (bf16 cast of x) lives in d_out scratch: its lifetime ends before
  // gemm_out, which overwrites every element of d_out.
  bf16* xb = (bf16*)d_out;

  dim3 tb(32, 8);
  transpose_w<<<dim3(24, 48), tb, 0, stream>>>(Wq, wqkvT, INDIM, HID);
  transpose_w<<<dim3(24, 48), tb, 0, stream>>>(Wk, wqkvT + (size_t)HID * INDIM, INDIM, HID);
  transpose_w<<<dim3(24, 48), tb, 0, stream>>>(Wv, wqkvT + (size_t)2 * HID * INDIM, INDIM, HID);
  transpose_w<<<dim3(48, 24), tb, 0, stream>>>(Wo, woT, HID, INDIM);

  convert_x<<<24576, 256, 0, stream>>>(x, xb);
  gemm_qkv<<<1152, 512, 0, stream>>>(xb, wqkvT, qkv);
  attn_kernel<<<8192, 256, 0, stream>>>(qkv, fcos, fsin, obuf);
  gemm_out<<<768, 512, 0, stream>>>(obuf, woT, bo, out);
}

// Round 4
// 684.333 us; speedup vs baseline: 1.3049x; 1.0324x over previous
//
#include <hip/hip_runtime.h>
#include <hip/hip_bf16.h>

using bf16 = __hip_bfloat16;
using short8 = __attribute__((ext_vector_type(8))) short;   // 8 bf16 (4 VGPRs)
using floatx4 = __attribute__((ext_vector_type(4))) float;  // 4 fp32 acc

#define NSEG 4
#define HID 768
#define INDIM 1536
#define NQKV 2304
#define NHEADS 8
#define HD 96

// fp32 -> bf16 bits, round-to-nearest-even
__device__ inline unsigned short f2b(float v) {
  union { float f; unsigned u; } c; c.f = v;
  unsigned r = c.u + 0x7FFF + ((c.u >> 16) & 1);
  return (unsigned short)(r >> 16);
}
// bf16 bits -> fp32
__device__ inline float b2f(unsigned short u) {
  union { unsigned v; float f; } c; c.v = ((unsigned)u) << 16; return c.f;
}

// async global->LDS, 16B per lane: dest = wave-uniform base + lane*16.
__device__ inline void gload16(const void* g, void* l) {
  __builtin_amdgcn_global_load_lds(
      (const __attribute__((address_space(1))) unsigned int*)g,
      (__attribute__((address_space(3))) unsigned int*)l, 16, 0, 0);
}

#define MEMFENCE asm volatile("" ::: "memory")
#define BARRIER do { MEMFENCE; __builtin_amdgcn_s_barrier(); MEMFENCE; } while (0)

// ---------------------------------------------------------------------------
// 8-phase 256x256 GEMM phase body (shared by both GEMMs).
// Expects in scope: lds, lA, lB, acc[8][4], bfr[4][2].
// LDS layout per parity: A at par*65536, B at 32768+par*65536; within a tile:
// [kh][row][32 bf16] (64B rows), st_16x32 swizzle: colbyte ^= 32 when row&8.
// ---------------------------------------------------------------------------
#define PHASE(par, q, LOADB, STAGES, VMW) do {                                 \
    short8 a00 = *(const short8*)(lA + (par)*65536 + (q)*2048);                \
    short8 a01 = *(const short8*)(lA + (par)*65536 + (q)*2048 + 16384);        \
    short8 a10 = *(const short8*)(lA + (par)*65536 + (q)*2048 + 1024);         \
    short8 a11 = *(const short8*)(lA + (par)*65536 + (q)*2048 + 1024 + 16384); \
    if (LOADB) {                                                               \
      _Pragma("unroll")                                                        \
      for (int fn = 0; fn < 4; ++fn) {                                         \
        bfr[fn][0] = *(const short8*)(lB + (par)*65536 + fn*1024);             \
        bfr[fn][1] = *(const short8*)(lB + (par)*65536 + fn*1024 + 16384);     \
      }                                                                        \
    }                                                                          \
    STAGES;                                                                    \
    BARRIER;                                                                   \
    __builtin_amdgcn_s_setprio(1);                                             \
    _Pragma("unroll")                                                          \
    for (int fn = 0; fn < 4; ++fn) {                                           \
      acc[2*(q)][fn]   = __builtin_amdgcn_mfma_f32_16x16x32_bf16(              \
          a00, bfr[fn][0], acc[2*(q)][fn], 0, 0, 0);                           \
      acc[2*(q)][fn]   = __builtin_amdgcn_mfma_f32_16x16x32_bf16(              \
          a01, bfr[fn][1], acc[2*(q)][fn], 0, 0, 0);                           \
      acc[2*(q)+1][fn] = __builtin_amdgcn_mfma_f32_16x16x32_bf16(              \
          a10, bfr[fn][0], acc[2*(q)+1][fn], 0, 0, 0);                         \
      acc[2*(q)+1][fn] = __builtin_amdgcn_mfma_f32_16x16x32_bf16(              \
          a11, bfr[fn][1], acc[2*(q)+1][fn], 0, 0, 0);                         \
    }                                                                          \
    __builtin_amdgcn_s_setprio(0);                                             \
    VMW;                                                                       \
    BARRIER;                                                                   \
  } while (0)

#define VM4 do { asm volatile("s_waitcnt vmcnt(4)" ::: "memory"); } while (0)
#define VM0 do { asm volatile("s_waitcnt vmcnt(0)" ::: "memory"); } while (0)

// ---------------------------------------------------------------------------
// Tiled transpose + fp32->bf16: src K x C fp32 row-major, dst C x K bf16.
// ---------------------------------------------------------------------------
__global__ __launch_bounds__(256) void transpose_w(
    const float* __restrict__ src, bf16* __restrict__ dst, int K, int C) {
  __shared__ unsigned short tile[32][33];
  const int c0 = blockIdx.x * 32, k0 = blockIdx.y * 32;
  const int tx = threadIdx.x, ty = threadIdx.y;  // 32 x 8
#pragma unroll
  for (int i = 0; i < 4; ++i)
    tile[ty + 8 * i][tx] = f2b(src[(size_t)(k0 + ty + 8 * i) * C + c0 + tx]);
  __syncthreads();
  unsigned short* d = (unsigned short*)dst;
#pragma unroll
  for (int i = 0; i < 4; ++i)
    d[(size_t)(c0 + ty + 8 * i) * K + k0 + tx] = tile[tx][ty + 8 * i];
}

// Same, for the three QKV weights in one launch (blockIdx.z picks source).
__global__ __launch_bounds__(256) void transpose_w3(
    const float* __restrict__ s0, const float* __restrict__ s1,
    const float* __restrict__ s2, bf16* __restrict__ dst) {
  __shared__ unsigned short tile[32][33];
  const float* srcs[3] = {s0, s1, s2};
  const float* src = srcs[blockIdx.z];
  bf16* dz = dst + (size_t)blockIdx.z * HID * INDIM;
  const int c0 = blockIdx.x * 32, k0 = blockIdx.y * 32;
  const int tx = threadIdx.x, ty = threadIdx.y;  // 32 x 8
#pragma unroll
  for (int i = 0; i < 4; ++i)
    tile[ty + 8 * i][tx] = f2b(src[(size_t)(k0 + ty + 8 * i) * HID + c0 + tx]);
  __syncthreads();
  unsigned short* d = (unsigned short*)dz;
#pragma unroll
  for (int i = 0; i < 4; ++i)
    d[(size_t)(c0 + ty + 8 * i) * INDIM + k0 + tx] = tile[tx][ty + 8 * i];
}

// ---------------------------------------------------------------------------
// One-time fp32 -> bf16 cast of x (same memory order). Memory-bound.
// ---------------------------------------------------------------------------
__global__ __launch_bounds__(256) void convert_x(
    const float* __restrict__ x, bf16* __restrict__ xb) {
  const size_t i = ((size_t)blockIdx.x * 256 + threadIdx.x) * 8;
  float4 a = *(const float4*)(x + i);
  float4 b = *(const float4*)(x + i + 4);
  union { uint4 u; unsigned short s[8]; } r;
  r.s[0] = f2b(a.x); r.s[1] = f2b(a.y); r.s[2] = f2b(a.z); r.s[3] = f2b(a.w);
  r.s[4] = f2b(b.x); r.s[5] = f2b(b.y); r.s[6] = f2b(b.z); r.s[7] = f2b(b.w);
  *(uint4*)(xb + i) = r.u;
}

// ---------------------------------------------------------------------------
// GEMM1: QKV[m][c] = sum_e A[m][e] * Wqkv[e][c]; 256x256 tile, 8-phase.
// A gathered from bf16 xb (B,T,H,W,D); BK=64 aligns with D=64 (p = kt).
// wT = Wqkv^T [2304][1536] bf16.
// ---------------------------------------------------------------------------
__global__ __launch_bounds__(512, 2) void gemm_qkv(
    const bf16* __restrict__ xb, const bf16* __restrict__ wT,
    bf16* __restrict__ qkv) {
  __shared__ __align__(16) char lds[131072];  // A0|B0|A1|B1, 32KB each
  const int tid = threadIdx.x;
  const int lane = tid & 63, wave = tid >> 6;
  const int wr = wave >> 2, wc = wave & 3;
  const int l15 = lane & 15, quad = lane >> 4;

  // XCD-aware block swizzle: 1152 blocks = 8 XCDs x 144
  const int lt = (blockIdx.x & 7) * 144 + (blockIdx.x >> 3);
  const int n0 = (lt % 9) * 256;
  const int m0 = (lt / 9) * 256;

  // --- staging source precompute (per-lane, kt-invariant) ---
  const int srow = wave * 16 + (lane >> 2);                 // 0..127 in half
  const int dswz = ((lane & 3) * 8) ^ ((lane & 32) >> 1);   // swizzled col
  const bf16* asrc[2];
  const bf16* bsrc[2];
#pragma unroll
  for (int h = 0; h < 2; ++h) {
    const int m = m0 + h * 128 + srow;
    const int r = m >> 2, n = m & 3;
    const int b = r >> 10, hw = r & 1023;
    asrc[h] = xb + ((size_t)((b * 96 + n * 24) * 1024 + hw)) * 64 + dswz;
    bsrc[h] = wT + (size_t)(n0 + h * 128 + srow) * INDIM + dswz;
  }
  char* sdst = lds + wave * 1024;  // wave-uniform LDS stage base

#define STAGE_QA(kt, h) do {                                   \
    char* d_ = sdst + (((kt) & 1) * 65536) + (h) * 8192;       \
    const bf16* s_ = asrc[h] + (size_t)(kt) * 65536;           \
    gload16(s_, d_);                                           \
    gload16(s_ + 32, d_ + 16384);                              \
  } while (0)
#define STAGE_QB(kt, h) do {                                   \
    char* d_ = sdst + 32768 + (((kt) & 1) * 65536) + (h) * 8192; \
    const bf16* s_ = bsrc[h] + (size_t)(kt) * 64;              \
    gload16(s_, d_);                                           \
    gload16(s_ + 32, d_ + 16384);                              \
  } while (0)

  // --- ds_read bases (swizzle is lane-constant: row&8 == l15&8) ---
  const int lofs = l15 * 64 + ((quad * 16) ^ ((l15 & 8) << 2));
  const char* lA = lds + wr * 8192 + lofs;
  const char* lB = lds + 32768 + wc * 4096 + lofs;

  floatx4 acc[8][4] = {};
  short8 bfr[4][2];

  // prologue: K0 fully + K1.B; land K0, keep K1.B in flight
  STAGE_QB(0, 0); STAGE_QB(0, 1); STAGE_QA(0, 0); STAGE_QA(0, 1);
  STAGE_QB(1, 0); STAGE_QB(1, 1);
  VM4;
  BARRIER;

  const int NKT = 24;
  for (int i = 0; i < 12; ++i) {
    const int a = 2 * i;
    PHASE(0, 0, 1, { STAGE_QA(a + 1, 0); }, {});
    PHASE(0, 1, 0, { STAGE_QA(a + 1, 1); }, {});
    PHASE(0, 2, 0, { if (a + 2 < NKT) STAGE_QB(a + 2, 0); }, {});
    PHASE(0, 3, 0, { if (a + 2 < NKT) STAGE_QB(a + 2, 1); },
          { if (a + 2 < NKT) VM4; else VM0; });
    PHASE(1, 0, 1, { if (a + 2 < NKT) STAGE_QA(a + 2, 0); }, {});
    PHASE(1, 1, 0, { if (a + 2 < NKT) STAGE_QA(a + 2, 1); }, {});
    PHASE(1, 2, 0, { if (a + 3 < NKT) STAGE_QB(a + 3, 0); }, {});
    PHASE(1, 3, 0, { if (a + 3 < NKT) STAGE_QB(a + 3, 1); },
          { if (a + 3 < NKT) VM4; else VM0; });
  }
#undef STAGE_QA
#undef STAGE_QB

  // epilogue: C/D layout col=lane&15, row=quad*4+reg
#pragma unroll
  for (int fm = 0; fm < 8; ++fm)
#pragma unroll
    for (int fn = 0; fn < 4; ++fn)
#pragma unroll
      for (int reg = 0; reg < 4; ++reg) {
        const int row = m0 + wr * 128 + fm * 16 + quad * 4 + reg;
        const int col = n0 + wc * 64 + fn * 16 + l15;
        qkv[(size_t)row * NQKV + col] = __float2bfloat16(acc[fm][fn][reg]);
      }
}

// ---------------------------------------------------------------------------
// Attention: one WAVE per row r (4 waves/block), pure-register, no LDS.
// hid=768 = 64 lanes x 12 cols; head = 96 cols = 8 lanes, so QK dots reduce
// with a 3-step shfl_xor butterfly inside each aligned 8-lane group.
// ---------------------------------------------------------------------------
__global__ __launch_bounds__(256) void attn_kernel(
    const bf16* __restrict__ qkv, const float* __restrict__ fcos,
    const float* __restrict__ fsin, bf16* __restrict__ obuf) {
  const int wave = threadIdx.x >> 6, lane = threadIdx.x & 63;
  const int r = blockIdx.x * 4 + wave;
  const int c0 = lane * 12;  // column base within hid (even; head l/8)
  const int j0 = lane * 6;   // rope pair base
  const bf16* base = qkv + (size_t)r * (NSEG * NQKV) + c0;

  float q[NSEG][12], k[NSEG][12];
#pragma unroll
  for (int n = 0; n < NSEG; ++n) {
    const bf16* row = base + (size_t)n * NQKV;
    union { uint2 u[3]; unsigned short s[12]; } Q, K;
#pragma unroll
    for (int t = 0; t < 3; ++t) {
      Q.u[t] = *(const uint2*)(row + 4 * t);
      K.u[t] = *(const uint2*)(row + HID + 4 * t);
    }
    const float* cp = fcos + n * (HID / 2) + j0;
    const float* sp = fsin + n * (HID / 2) + j0;
#pragma unroll
    for (int t = 0; t < 6; ++t) {
      const float cc = cp[t], ss = sp[t];
      const float a = b2f(Q.s[2 * t]), b = b2f(Q.s[2 * t + 1]);
      q[n][2 * t] = a * cc - b * ss;
      q[n][2 * t + 1] = a * ss + b * cc;
      const float e = b2f(K.s[2 * t]), f = b2f(K.s[2 * t + 1]);
      k[n][2 * t] = e * cc - f * ss;
      k[n][2 * t + 1] = e * ss + f * cc;
    }
  }

  // scores + 8-lane butterfly reduce; every lane ends with full S[h][n][m]
  float P[NSEG][NSEG];
#pragma unroll
  for (int n = 0; n < NSEG; ++n)
#pragma unroll
    for (int m = 0; m < NSEG; ++m) {
      float s = 0.f;
#pragma unroll
      for (int t = 0; t < 12; ++t) s += q[n][t] * k[m][t];
      s += __shfl_xor(s, 1, 64);
      s += __shfl_xor(s, 2, 64);
      s += __shfl_xor(s, 4, 64);
      P[n][m] = s * 0.10206207261596575f;  // 1/sqrt(96)
    }
  // softmax over m (computed redundantly per lane)
#pragma unroll
  for (int n = 0; n < NSEG; ++n) {
    const float mx = fmaxf(fmaxf(P[n][0], P[n][1]), fmaxf(P[n][2], P[n][3]));
    float sum = 0.f;
#pragma unroll
    for (int m = 0; m < NSEG; ++m) {
      P[n][m] = __expf(P[n][m] - mx);
      sum += P[n][m];
    }
    const float inv = 1.f / sum;
#pragma unroll
    for (int m = 0; m < NSEG; ++m) P[n][m] *= inv;
  }

  // load v late (keeps peak VGPR down), PV, pack bf16, store
  float v[NSEG][12];
#pragma unroll
  for (int n = 0; n < NSEG; ++n) {
    union { uint2 u[3]; unsigned short s[12]; } V;
#pragma unroll
    for (int t = 0; t < 3; ++t)
      V.u[t] = *(const uint2*)(base + (size_t)n * NQKV + 2 * HID + 4 * t);
#pragma unroll
    for (int t = 0; t < 12; ++t) v[n][t] = b2f(V.s[t]);
  }
  bf16* orow = obuf + (size_t)r * (NSEG * HID) + c0;
#pragma unroll
  for (int n = 0; n < NSEG; ++n) {
    union { uint2 u[3]; unsigned w[6]; } O;
#pragma unroll
    for (int t = 0; t < 6; ++t) {
      float o0 = 0.f, o1 = 0.f;
#pragma unroll
      for (int m = 0; m < NSEG; ++m) {
        o0 += P[n][m] * v[m][2 * t];
        o1 += P[n][m] * v[m][2 * t + 1];
      }
      O.w[t] = (unsigned)f2b(o0) | ((unsigned)f2b(o1) << 16);
    }
#pragma unroll
    for (int t = 0; t < 3; ++t)
      *(uint2*)(orow + (size_t)n * HID + 4 * t) = O.u[t];
  }
}

// ---------------------------------------------------------------------------
// GEMM2: out = O @ Wo + bo, fused scatter into (B,T,H,W,D) fp32 output.
//   A = obuf [32768][768] bf16, wT = Wo^T [1536][768] bf16. 8-phase 256x256.
// ---------------------------------------------------------------------------
__global__ __launch_bounds__(512, 2) void gemm_out(
    const bf16* __restrict__ Ao, const bf16* __restrict__ wT,
    const float* __restrict__ bo, float* __restrict__ out) {
  __shared__ __align__(16) char lds[131072];
  const int tid = threadIdx.x;
  const int lane = tid & 63, wave = tid >> 6;
  const int wr = wave >> 2, wc = wave & 3;
  const int l15 = lane & 15, quad = lane >> 4;

  // XCD-aware block swizzle: 768 blocks = 8 XCDs x 96
  const int lt = (blockIdx.x & 7) * 96 + (blockIdx.x >> 3);
  const int n0 = (lt % 6) * 256;
  const int m0 = (lt / 6) * 256;

  const int srow = wave * 16 + (lane >> 2);
  const int dswz = ((lane & 3) * 8) ^ ((lane & 32) >> 1);
  const bf16* asrc[2];
  const bf16* bsrc[2];
#pragma unroll
  for (int h = 0; h < 2; ++h) {
    asrc[h] = Ao + (size_t)(m0 + h * 128 + srow) * HID + dswz;
    bsrc[h] = wT + (size_t)(n0 + h * 128 + srow) * HID + dswz;
  }
  char* sdst = lds + wave * 1024;

#define STAGE_OA(kt, h) do {                                   \
    char* d_ = sdst + (((kt) & 1) * 65536) + (h) * 8192;       \
    const bf16* s_ = asrc[h] + (size_t)(kt) * 64;              \
    gload16(s_, d_);                                           \
    gload16(s_ + 32, d_ + 16384);                              \
  } while (0)
#define STAGE_OB(kt, h) do {                                   \
    char* d_ = sdst + 32768 + (((kt) & 1) * 65536) + (h) * 8192; \
    const bf16* s_ = bsrc[h] + (size_t)(kt) * 64;              \
    gload16(s_, d_);                                           \
    gload16(s_ + 32, d_ + 16384);                              \
  } while (0)

  const int lofs = l15 * 64 + ((quad * 16) ^ ((l15 & 8) << 2));
  const char* lA = lds + wr * 8192 + lofs;
  const char* lB = lds + 32768 + wc * 4096 + lofs;

  floatx4 acc[8][4] = {};
  short8 bfr[4][2];

  STAGE_OB(0, 0); STAGE_OB(0, 1); STAGE_OA(0, 0); STAGE_OA(0, 1);
  STAGE_OB(1, 0); STAGE_OB(1, 1);
  VM4;
  BARRIER;

  const int NKT = 12;
  for (int i = 0; i < 6; ++i) {
    const int a = 2 * i;
    PHASE(0, 0, 1, { STAGE_OA(a + 1, 0); }, {});
    PHASE(0, 1, 0, { STAGE_OA(a + 1, 1); }, {});
    PHASE(0, 2, 0, { if (a + 2 < NKT) STAGE_OB(a + 2, 0); }, {});
    PHASE(0, 3, 0, { if (a + 2 < NKT) STAGE_OB(a + 2, 1); },
          { if (a + 2 < NKT) VM4; else VM0; });
    PHASE(1, 0, 1, { if (a + 2 < NKT) STAGE_OA(a + 2, 0); }, {});
    PHASE(1, 1, 0, { if (a + 2 < NKT) STAGE_OA(a + 2, 1); }, {});
    PHASE(1, 2, 0, { if (a + 3 < NKT) STAGE_OB(a + 3, 0); }, {});
    PHASE(1, 3, 0, { if (a + 3 < NKT) STAGE_OB(a + 3, 1); },
          { if (a + 3 < NKT) VM4; else VM0; });
  }
#undef STAGE_OA
#undef STAGE_OB

  // epilogue: bias + scatter to (B,T,H,W,D) fp32: t = n*24+p
#pragma unroll
  for (int fm = 0; fm < 8; ++fm)
#pragma unroll
    for (int fn = 0; fn < 4; ++fn)
#pragma unroll
      for (int reg = 0; reg < 4; ++reg) {
        const int row = m0 + wr * 128 + fm * 16 + quad * 4 + reg;
        const int col = n0 + wc * 64 + fn * 16 + l15;
        const float v = acc[fm][fn][reg] + bo[col];
        const int r = row >> 2, n = row & 3;
        const int b = r >> 10, hw = r & 1023;
        const int p = col >> 6, d = col & 63;
        const size_t dst =
            ((size_t)((b * 96 + n * 24 + p) * 1024 + hw)) * 64 + d;
        out[dst] = v;
      }
}

// ---------------------------------------------------------------------------
extern "C" void kernel_launch(void* const* d_in, const int* in_sizes, int n_in,
                              void* d_out, int out_size, void* d_ws,
                              size_t ws_size, hipStream_t stream) {
  const float* x = (const float*)d_in[0];     // (8,96,32,32,64) fp32
  const float* fcos = (const float*)d_in[1];  // (4,384) fp32
  const float* fsin = (const float*)d_in[2];  // (4,384) fp32
  const float* Wq = (const float*)d_in[3];    // (1536,768) fp32
  const float* Wk = (const float*)d_in[4];
  const float* Wv = (const float*)d_in[5];
  const float* Wo = (const float*)d_in[6];    // (768,1536) fp32
  const float* bo = (const float*)d_in[7];    // (1536,) fp32
  float* out = (float*)d_out;                 // (8,96,32,32,64) fp32

  char* ws = (char*)d_ws;
  bf16* wqkvT = (bf16*)ws;                        // 2304*1536*2 = 7,077,888 B
  bf16* woT = (bf16*)(ws + 7077888);              // 1536*768*2  = 2,359,296 B
  bf16* qkv = (bf16*)(ws + 9437184);              // 32768*2304*2 = 150,994,944 B
  bf16* obuf = (bf16*)(ws + 160432128);           // 32768*768*2  = 50,331,648 B
  // xb (bf16 cast of x) lives in d_out scratch: its lifetime ends before
  // gemm_out, which overwrites every element of d_out.
  bf16* xb = (bf16*)d_out;

  dim3 tb(32, 8);
  transpose_w3<<<dim3(24, 48, 3), tb, 0, stream>>>(Wq, Wk, Wv, wqkvT);
  transpose_w<<<dim3(48, 24), tb, 0, stream>>>(Wo, woT, HID, INDIM);

  convert_x<<<24576, 256, 0, stream>>>(x, xb);
  gemm_qkv<<<1152, 512, 0, stream>>>(xb, wqkvT, qkv);
  attn_kernel<<<2048, 256, 0, stream>>>(qkv, fcos, fsin, obuf);
  gemm_out<<<768, 512, 0, stream>>>(obuf, woT, bo, out);
}